// Round 11
// baseline (418.420 us; speedup 1.0000x reference)
//
#include <hip/hip_runtime.h>
#include <hip/hip_bf16.h>

#define NEG 0.2f
#define BK_SHIFT 9       // 512 nodes per bucket
#define BK_CAP 9216      // slots per bucket (mean ~8192, sigma ~90 -> 11 sigma headroom)

typedef short short8 __attribute__((ext_vector_type(8)));   // 8 bf16 (4 VGPRs)
typedef float f32x4 __attribute__((ext_vector_type(4)));

__device__ __forceinline__ float lrelu(float x){ return x > 0.f ? x : NEG * x; }
__device__ __forceinline__ float elu_f(float x){ return x > 0.f ? x : expm1f(x); }
__device__ __forceinline__ unsigned short f2bf(float f){
  unsigned int u = __float_as_uint(f);
  unsigned int r = u + 0x7fffu + ((u >> 16) & 1u);   // round-to-nearest-even
  return (unsigned short)(r >> 16);
}
__device__ __forceinline__ float bf2f(unsigned short u){
  return __uint_as_float(((unsigned int)u) << 16);
}

// ---------------- CSR build ----------------
// Phase A: bin edges into bucket-major ebuf (contiguous runs -> no write-allocate blowup).
// ebuf stores are nontemporal (written once, read by csrC -> skip RFO).
// Last block instead packs W1 -> bf16 transposed Wp (folds the packW dispatch).
__global__ __launch_bounds__(512) void k_binA(
    const int* __restrict__ src, const int* __restrict__ dst, int E,
    int* __restrict__ gcursor, int2* __restrict__ ebuf,
    const float* __restrict__ W, unsigned short* __restrict__ Wp){
  __shared__ int hist[256];
  __shared__ int base[256];
  int t = threadIdx.x;
  if (blockIdx.x == gridDim.x - 1){
    // packW: 128x128, Wp[n][k] = bf16(W[k][n])
    for (int j = 0; j < 32; j++){
      int idx = j * 512 + t;
      int n = idx >> 7, k = idx & 127;
      Wp[n * 128 + k] = f2bf(W[(size_t)k * 128 + n]);
    }
    return;
  }
  if (t < 256) hist[t] = 0;
  __syncthreads();
  int e0 = blockIdx.x * 4096;
  for (int j = 0; j < 8; j++){
    int e = e0 + j * 512 + t;
    if (e < E) atomicAdd(&hist[dst[e] >> BK_SHIFT], 1);
  }
  __syncthreads();
  if (t < 256){
    int cnt = hist[t];
    if (cnt > 0) base[t] = atomicAdd(&gcursor[t], cnt);
    hist[t] = 0;                 // reuse as local placement cursor
  }
  __syncthreads();
  for (int j = 0; j < 8; j++){
    int e = e0 + j * 512 + t;
    if (e < E){
      int d = dst[e]; int b = d >> BK_SHIFT;
      int loc = atomicAdd(&hist[b], 1);
      unsigned long long pk = ((unsigned long long)(unsigned)d << 32) | (unsigned)src[e];
      __builtin_nontemporal_store(pk,
        (unsigned long long*)&ebuf[(size_t)b * BK_CAP + base[b] + loc]);
    }
  }
}

// csrC: per-bucket CSR build, 1024 threads. Inlines the bucket-base scan, then
// deg-histogram + LDS scan -> rowp, then placement replay (ebuf L2-warm).
// Self-loop at rowp[n]+deg[n].
__global__ __launch_bounds__(1024) void k_csrC(
    const int2* __restrict__ ebuf, const int* __restrict__ gcount,
    int* __restrict__ rowp, int* __restrict__ csr, int N, int NBK, int total){
  __shared__ int hist[512];
  __shared__ int psum[256];
  __shared__ int bsum[256];
  int b = blockIdx.x, t = threadIdx.x;
  int nbase = b << BK_SHIFT;
  int cnt = gcount[b];
  const int2* eb = ebuf + (size_t)b * BK_CAP;
  if (t < 512) hist[t] = 0;
  int bv = 0;
  if (t < 256){
    int nodes = 0;
    if (t < NBK){ int nb = N - (t << BK_SHIFT); nodes = nb > 512 ? 512 : nb; bv = gcount[t] + nodes; }
    bsum[t] = bv;
  }
  __syncthreads();
  for (int off = 1; off < 256; off <<= 1){
    int x = (t >= off && t < 256) ? bsum[t - off] : 0;
    __syncthreads();
    if (t < 256) bsum[t] += x;
    __syncthreads();
  }
  for (int i = t; i < cnt; i += 1024)
    atomicAdd(&hist[eb[i].y - nbase], 1);
  __syncthreads();
  int v0 = 0, v1 = 0, ps = 0;
  if (t < 256){ v0 = hist[2 * t]; v1 = hist[2 * t + 1]; ps = v0 + v1; psum[t] = ps; }
  __syncthreads();
  for (int off = 1; off < 256; off <<= 1){
    int x = (t >= off && t < 256) ? psum[t - off] : 0;
    __syncthreads();
    if (t < 256) psum[t] += x;
    __syncthreads();
  }
  if (t < 256){
    int eo = psum[t] - ps;               // exclusive deg-sum at node 2t
    int bb = (b == 0) ? 0 : bsum[b - 1];
    int n0 = 2 * t, n1 = 2 * t + 1;
    int r0 = bb + eo + n0;               // +n0: one self-loop slot per prior node
    int r1 = bb + eo + v0 + n1;
    if (nbase + n0 < N) rowp[nbase + n0] = r0;
    if (nbase + n1 < N) rowp[nbase + n1] = r1;
    hist[n0] = r0; hist[n1] = r1;        // reuse as cursors
  }
  if (b == 0 && t == 0) rowp[N] = total;
  __syncthreads();
  for (int i = t; i < cnt; i += 1024){
    int2 e = eb[i];
    int pos = atomicAdd(&hist[e.y - nbase], 1);
    csr[pos] = e.x;
  }
  __syncthreads();
  if (t < 256){
    int n0 = 2 * t, n1 = 2 * t + 1;
    if (nbase + n0 < N) csr[hist[n0]] = nbase + n0;
    if (nbase + n1 < N) csr[hist[n1]] = nbase + n1;
  }
}

// ---------------- GEMM1 (MFMA bf16): x[N,128] @ W[128,128] -> h_bf[N,128], + ss1/sd1 fused
// 64 rows x 128 cols / block; 4 waves, each 16 rows x 128 cols as 8 col-tiles of 16x16x32 MFMA.
// D layout: row = quad*4+reg, col = ct*16 + (lane&15).
__global__ __launch_bounds__(256, 3) void k_gemm1(
    const float* __restrict__ x, const unsigned short* __restrict__ Wp,
    const float* __restrict__ a_src, const float* __restrict__ a_dst,
    unsigned short* __restrict__ h_bf, float* __restrict__ ss, float* __restrict__ sd, int N){
  __shared__ unsigned short Wt[128 * 136];   // Wt[n][k], stride 136 (2-way bank alias: free)
  __shared__ unsigned short Xb[64 * 136];    // Xb[row][k], stride 136
  int t = threadIdx.x;
  int rb = blockIdx.x * 64;

  // stage pre-packed W' (32 KB) via uint4: 2048 items = 128 cols x 16 chunks of 8 shorts
  #pragma unroll
  for (int j = 0; j < 8; j++){
    int fi = j * 256 + t;
    int n = fi >> 4, ch = fi & 15;
    *(uint4*)&Wt[n * 136 + ch * 8] = *(const uint4*)&Wp[n * 128 + ch * 8];
  }
  // stage X rows as bf16
  #pragma unroll
  for (int j = 0; j < 8; j++){
    int fi = j * 256 + t;           // 0..2047
    int row = fi >> 5, k4 = (fi & 31) * 4;
    int gr = rb + row;
    float4 v = make_float4(0.f, 0.f, 0.f, 0.f);
    if (gr < N) v = *(const float4*)&x[(size_t)gr * 128 + k4];
    uint2 pk;
    pk.x = ((unsigned)f2bf(v.y) << 16) | f2bf(v.x);
    pk.y = ((unsigned)f2bf(v.w) << 16) | f2bf(v.z);
    *(uint2*)&Xb[row * 136 + k4] = pk;
  }
  __syncthreads();

  int w = t >> 6, l = t & 63;
  int m = l & 15, quad = l >> 4;
  f32x4 acc[8];
  #pragma unroll
  for (int ct = 0; ct < 8; ct++) acc[ct] = (f32x4){0.f, 0.f, 0.f, 0.f};

  #pragma unroll
  for (int kc = 0; kc < 4; kc++){
    short8 a = *(const short8*)&Xb[(w * 16 + m) * 136 + kc * 32 + quad * 8];
    #pragma unroll
    for (int ct = 0; ct < 8; ct++){
      short8 b = *(const short8*)&Wt[(ct * 16 + m) * 136 + kc * 32 + quad * 8];
      acc[ct] = __builtin_amdgcn_mfma_f32_16x16x32_bf16(a, b, acc[ct], 0, 0, 0);
    }
  }

  float as[8], ad[8];
  #pragma unroll
  for (int ct = 0; ct < 8; ct++){ as[ct] = a_src[ct * 16 + m]; ad[ct] = a_dst[ct * 16 + m]; }

  #pragma unroll
  for (int reg = 0; reg < 4; reg++){
    int gr = rb + w * 16 + quad * 4 + reg;
    bool ok = gr < N;
    if (ok){
      #pragma unroll
      for (int ct = 0; ct < 8; ct++)
        h_bf[(size_t)gr * 128 + ct * 16 + m] = f2bf(acc[ct][reg]);
    }
    #pragma unroll
    for (int hh = 0; hh < 4; hh++){
      float ps = acc[2*hh][reg] * as[2*hh] + acc[2*hh+1][reg] * as[2*hh+1];
      float pd = acc[2*hh][reg] * ad[2*hh] + acc[2*hh+1][reg] * ad[2*hh+1];
      ps += __shfl_xor(ps, 1, 16); ps += __shfl_xor(ps, 2, 16);
      ps += __shfl_xor(ps, 4, 16); ps += __shfl_xor(ps, 8, 16);
      pd += __shfl_xor(pd, 1, 16); pd += __shfl_xor(pd, 2, 16);
      pd += __shfl_xor(pd, 4, 16); pd += __shfl_xor(pd, 8, 16);
      if (m == 0 && ok){ ss[(size_t)gr * 4 + hh] = ps; sd[(size_t)gr * 4 + hh] = pd; }
    }
  }
}

// ---------------- agg1: 1 wave per node; x8 edge unroll (8 gathers in flight) ----------------
__global__ __launch_bounds__(256) void k_agg1(
    const int* __restrict__ row_ptr, const int* __restrict__ csr_src,
    const float* __restrict__ ss, const float* __restrict__ sdst,
    const __hip_bfloat162* __restrict__ hb2,
    unsigned int* __restrict__ out1_bf, int N){
  int n = blockIdx.x * 4 + (threadIdx.x >> 6);
  if (n >= N) return;
  int l = threadIdx.x & 63;
  int hd = l >> 4;                 // this lane's head (channels 2l, 2l+1)
  float sdv = sdst[(size_t)n * 4 + hd];
  int j8 = l & 7, hh8 = (l >> 3) & 3;    // x8: lanes (mod 32) cover edge x head grid
  float sw8 = sdst[(size_t)n * 4 + hh8];
  int j4 = l & 3, hh4 = (l >> 2) & 3;    // x4 tail mapping
  float sw4 = sdst[(size_t)n * 4 + hh4];
  int beg = row_ptr[n], end = row_ptr[n + 1];
  float ax = 0.f, ay = 0.f, sw = 0.f;
  int e = beg;
  for (; e + 8 <= end; e += 8){
    int sj = csr_src[e + j8];
    float wv = __expf(lrelu(ss[(size_t)sj * 4 + hh8] + sw8));
    int s0 = __shfl(sj, 0, 8), s1 = __shfl(sj, 1, 8), s2 = __shfl(sj, 2, 8), s3 = __shfl(sj, 3, 8);
    int s4 = __shfl(sj, 4, 8), s5 = __shfl(sj, 5, 8), s6 = __shfl(sj, 6, 8), s7 = __shfl(sj, 7, 8);
    float w0 = __shfl(wv, hd * 8 + 0, 32), w1 = __shfl(wv, hd * 8 + 1, 32);
    float w2 = __shfl(wv, hd * 8 + 2, 32), w3 = __shfl(wv, hd * 8 + 3, 32);
    float w4 = __shfl(wv, hd * 8 + 4, 32), w5 = __shfl(wv, hd * 8 + 5, 32);
    float w6 = __shfl(wv, hd * 8 + 6, 32), w7 = __shfl(wv, hd * 8 + 7, 32);
    float2 v0 = __bfloat1622float2(hb2[(size_t)s0 * 64 + l]);
    float2 v1 = __bfloat1622float2(hb2[(size_t)s1 * 64 + l]);
    float2 v2 = __bfloat1622float2(hb2[(size_t)s2 * 64 + l]);
    float2 v3 = __bfloat1622float2(hb2[(size_t)s3 * 64 + l]);
    float2 v4 = __bfloat1622float2(hb2[(size_t)s4 * 64 + l]);
    float2 v5 = __bfloat1622float2(hb2[(size_t)s5 * 64 + l]);
    float2 v6 = __bfloat1622float2(hb2[(size_t)s6 * 64 + l]);
    float2 v7 = __bfloat1622float2(hb2[(size_t)s7 * 64 + l]);
    ax += w0*v0.x + w1*v1.x + w2*v2.x + w3*v3.x + w4*v4.x + w5*v5.x + w6*v6.x + w7*v7.x;
    ay += w0*v0.y + w1*v1.y + w2*v2.y + w3*v3.y + w4*v4.y + w5*v5.y + w6*v6.y + w7*v7.y;
    sw += w0 + w1 + w2 + w3 + w4 + w5 + w6 + w7;
  }
  for (; e + 4 <= end; e += 4){
    int sj = csr_src[e + j4];
    float wv = __expf(lrelu(ss[(size_t)sj * 4 + hh4] + sw4));
    int s0 = __shfl(sj, 0, 4), s1 = __shfl(sj, 1, 4);
    int s2 = __shfl(sj, 2, 4), s3 = __shfl(sj, 3, 4);
    float w0 = __shfl(wv, hd * 4 + 0, 16), w1 = __shfl(wv, hd * 4 + 1, 16);
    float w2 = __shfl(wv, hd * 4 + 2, 16), w3 = __shfl(wv, hd * 4 + 3, 16);
    float2 v0 = __bfloat1622float2(hb2[(size_t)s0 * 64 + l]);
    float2 v1 = __bfloat1622float2(hb2[(size_t)s1 * 64 + l]);
    float2 v2 = __bfloat1622float2(hb2[(size_t)s2 * 64 + l]);
    float2 v3 = __bfloat1622float2(hb2[(size_t)s3 * 64 + l]);
    ax += w0*v0.x + w1*v1.x + w2*v2.x + w3*v3.x;
    ay += w0*v0.y + w1*v1.y + w2*v2.y + w3*v3.y;
    sw += w0 + w1 + w2 + w3;
  }
  for (; e < end; e++){
    int s = csr_src[e];
    float w = __expf(lrelu(ss[(size_t)s * 4 + hd] + sdv));
    float2 v = __bfloat1622float2(hb2[(size_t)s * 64 + l]);
    ax += w*v.x; ay += w*v.y; sw += w;
  }
  float inv = 1.f / (sw + 1e-16f);
  unsigned int lo = f2bf(ax * inv), hi = f2bf(ay * inv);
  out1_bf[(size_t)n * 64 + l] = (hi << 16) | lo;
}

// ---------------- GEMM2: elu(out1_bf+b1)[N,128] @ W2[128,32] -> h2_bf[N,32], + s_src2/s_dst2[N]
__global__ __launch_bounds__(256) void k_gemm2(
    const unsigned int* __restrict__ out1_bf, const float* __restrict__ b1,
    const float* __restrict__ W2,
    const float* __restrict__ a_src, const float* __restrict__ a_dst,
    unsigned short* __restrict__ h2_bf, float* __restrict__ s_src2, float* __restrict__ s_dst2, int N){
  __shared__ __align__(16) float Wl[128 * 32];
  __shared__ __align__(16) float Xl[64 * 132];
  int t = threadIdx.x;
  int rb = blockIdx.x * 64;

  const float4* Wg4 = (const float4*)W2;
  float4* Wl4 = (float4*)Wl;
  #pragma unroll
  for (int j = 0; j < 4; j++) Wl4[j * 256 + t] = Wg4[j * 256 + t];

  // out1_bf row = 64 uints; q covers channels q*8..q*8+7 -> uint offset q*4
  #pragma unroll
  for (int j = 0; j < 4; j++){
    int fi = j * 256 + t;               // 0..1023
    int row = fi >> 4, q = fi & 15;     // q: 8-channel group
    int gr = rb + row;
    float v[8] = {0.f,0.f,0.f,0.f,0.f,0.f,0.f,0.f};
    if (gr < N){
      uint4 u = *(const uint4*)&out1_bf[(size_t)gr * 64 + q * 4];
      float4 bva = *(const float4*)&b1[q * 8];
      float4 bvb = *(const float4*)&b1[q * 8 + 4];
      v[0] = elu_f(bf2f((unsigned short)(u.x & 0xffff)) + bva.x);
      v[1] = elu_f(bf2f((unsigned short)(u.x >> 16))    + bva.y);
      v[2] = elu_f(bf2f((unsigned short)(u.y & 0xffff)) + bva.z);
      v[3] = elu_f(bf2f((unsigned short)(u.y >> 16))    + bva.w);
      v[4] = elu_f(bf2f((unsigned short)(u.z & 0xffff)) + bvb.x);
      v[5] = elu_f(bf2f((unsigned short)(u.z >> 16))    + bvb.y);
      v[6] = elu_f(bf2f((unsigned short)(u.w & 0xffff)) + bvb.z);
      v[7] = elu_f(bf2f((unsigned short)(u.w >> 16))    + bvb.w);
    }
    #pragma unroll
    for (int i = 0; i < 8; i++) Xl[row * 132 + q * 8 + i] = v[i];
  }
  __syncthreads();

  int cg = t & 7, rg = t >> 3;
  int c0 = cg * 4, r0 = rg * 2;
  float acc[2][4] = {};

  #pragma unroll 8
  for (int k = 0; k < 128; k++){
    float a0 = Xl[r0 * 132 + k];
    float a1 = Xl[(r0 + 1) * 132 + k];
    float4 b = *(float4*)&Wl[k * 32 + c0];
    acc[0][0] += a0 * b.x; acc[0][1] += a0 * b.y; acc[0][2] += a0 * b.z; acc[0][3] += a0 * b.w;
    acc[1][0] += a1 * b.x; acc[1][1] += a1 * b.y; acc[1][2] += a1 * b.z; acc[1][3] += a1 * b.w;
  }

  float as[4], ad[4];
  #pragma unroll
  for (int j = 0; j < 4; j++){ as[j] = a_src[c0 + j]; ad[j] = a_dst[c0 + j]; }
  #pragma unroll
  for (int i = 0; i < 2; i++){
    int row = rb + r0 + i;
    if (row < N){
      ushort4 o;
      o.x = f2bf(acc[i][0]); o.y = f2bf(acc[i][1]); o.z = f2bf(acc[i][2]); o.w = f2bf(acc[i][3]);
      *(ushort4*)&h2_bf[(size_t)row * 32 + c0] = o;
    }
    float ps = 0.f, pd = 0.f;
    #pragma unroll
    for (int j = 0; j < 4; j++){ ps += acc[i][j] * as[j]; pd += acc[i][j] * ad[j]; }
    ps += __shfl_xor(ps, 1, 8); ps += __shfl_xor(ps, 2, 8); ps += __shfl_xor(ps, 4, 8);
    pd += __shfl_xor(pd, 1, 8); pd += __shfl_xor(pd, 2, 8); pd += __shfl_xor(pd, 4, 8);
    if ((t & 7) == 0 && row < N){ s_src2[row] = ps; s_dst2[row] = pd; }
  }
}

// ---------------- agg2: 8 nodes/block (32 ch each), 2-chunk L2-resident gather ----------------
// h2_bf is 6.4 MB > 4 MB per-XCD L2; chunking src into halves keeps each pass's working
// set (3.2 MB) L2-resident -> random 64 B gathers become L2 hits instead of 128 B-line misses.
// Branch per edge is wave-uniform (all 32 lanes share s). Same values, different sum order.
__global__ __launch_bounds__(256) void k_agg2(
    const int* __restrict__ row_ptr, const int* __restrict__ csr_src,
    const float* __restrict__ ss2, const float* __restrict__ sd2,
    const unsigned short* __restrict__ h2bf, const float* __restrict__ b2,
    float* __restrict__ out, int N, int HALF){
  int n = blockIdx.x * 8 + (threadIdx.x >> 5);
  if (n >= N) return;
  int c = threadIdx.x & 31;
  float sdv = sd2[n];
  int beg = row_ptr[n], end = row_ptr[n + 1];
  float acc = 0.f, sw = 0.f;
  #pragma unroll 1
  for (int p = 0; p < 2; p++){
    bool lowpass = (p == 0);
    int e = beg;
    for (; e + 2 <= end; e += 2){
      int s0 = csr_src[e], s1 = csr_src[e + 1];
      if ((s0 < HALF) == lowpass){
        float w = __expf(lrelu(ss2[s0] + sdv));
        acc += w * bf2f(h2bf[(size_t)s0 * 32 + c]); sw += w;
      }
      if ((s1 < HALF) == lowpass){
        float w = __expf(lrelu(ss2[s1] + sdv));
        acc += w * bf2f(h2bf[(size_t)s1 * 32 + c]); sw += w;
      }
    }
    for (; e < end; e++){
      int s = csr_src[e];
      if ((s < HALF) == lowpass){
        float w = __expf(lrelu(ss2[s] + sdv));
        acc += w * bf2f(h2bf[(size_t)s * 32 + c]); sw += w;
      }
    }
  }
  out[(size_t)n * 32 + c] = acc / (sw + 1e-16f) + b2[c];
}

extern "C" void kernel_launch(void* const* d_in, const int* in_sizes, int n_in,
                              void* d_out, int out_size, void* d_ws, size_t ws_size,
                              hipStream_t stream) {
  const float* x      = (const float*)d_in[0];
  const int*   ei     = (const int*)  d_in[1];
  const float* W1     = (const float*)d_in[2];
  const float* a_src1 = (const float*)d_in[3];
  const float* a_dst1 = (const float*)d_in[4];
  const float* b1     = (const float*)d_in[5];
  const float* W2     = (const float*)d_in[6];
  const float* a_src2 = (const float*)d_in[7];
  const float* a_dst2 = (const float*)d_in[8];
  const float* b2     = (const float*)d_in[9];
  float* out = (float*)d_out;

  int N = in_sizes[0] / 128;
  int E = in_sizes[1] / 2;
  const int* srcp = ei;
  const int* dstp = ei + E;
  int total = E + N;
  int NBK = (N + 511) >> 9;       // buckets of 512 nodes

  char* p = (char*)d_ws;
  auto alloc = [&](size_t bytes) -> void* {
    void* r = (void*)p; p += (bytes + 255) & ~(size_t)255; return r;
  };
  unsigned short* h_bf    = (unsigned short*)alloc((size_t)N * 128 * 2);
  unsigned int*   out1_bf = (unsigned int*)alloc((size_t)N * 64 * 4);   // 128 bf16/row packed as 64 uint
  unsigned short* h2_bf   = (unsigned short*)alloc((size_t)N * 32 * 2);
  unsigned short* Wp      = (unsigned short*)alloc(128 * 128 * 2);
  float* ss1  = (float*)alloc((size_t)N * 4 * 4);
  float* sd1  = (float*)alloc((size_t)N * 4 * 4);
  float* ss2  = (float*)alloc((size_t)N * 4);
  float* sd2  = (float*)alloc((size_t)N * 4);
  int* rowp   = (int*)alloc((size_t)(N + 1) * 4);
  int* csr    = (int*)alloc((size_t)total * 4);
  int* gcur   = (int*)alloc(256 * 4);
  // ebuf (bucket staging, 196*9216*8 = 14.5 MB) aliases out1_bf (25.6 MB):
  // lifetimes disjoint (ebuf: binA..csrC; out1_bf: agg1..gemm2)
  int2* ebuf  = (int2*)out1_bf;
  (void)ws_size; (void)n_in; (void)out_size;

  hipMemsetAsync(gcur, 0, 256 * 4, stream);
  int EB = (E + 4095) / 4096;
  k_binA<<<EB + 1, 512, 0, stream>>>(srcp, dstp, E, gcur, ebuf, W1, Wp);
  k_csrC<<<NBK, 1024, 0, stream>>>(ebuf, gcur, rowp, csr, N, NBK, total);

  k_gemm1<<<(N + 63) / 64, 256, 0, stream>>>(x, Wp, a_src1, a_dst1, h_bf, ss1, sd1, N);
  k_agg1<<<(N + 3) / 4, 256, 0, stream>>>(rowp, csr, ss1, sd1, (const __hip_bfloat162*)h_bf, out1_bf, N);
  k_gemm2<<<(N + 63) / 64, 256, 0, stream>>>(out1_bf, b1, W2, a_src2, a_dst2, h2_bf, ss2, sd2, N);
  k_agg2<<<(N + 7) / 8, 256, 0, stream>>>(rowp, csr, ss2, sd2, h2_bf, b2, out, N, N / 2);
}